// Round 3
// baseline (199.785 us; speedup 1.0000x reference)
//
#include <hip/hip_runtime.h>
#include <hip/hip_cooperative_groups.h>
#include <math.h>

namespace cg = cooperative_groups;

#define H 256
#define V 10000
#define COLSN 64
#define ROWSN 200000
#define T_STEPS 4
#define QLEN 40
#define NNUM 5
#define NOPS 9

// workspace float offsets
#define WS_XWB   0          // 40*256 : X@Wx + b
#define WS_Q     10240      // 256
#define WS_HHA   10496      // 256 (h_hist ping)
#define WS_HHB   10752      // 256 (h_hist pong)
#define WS_POP   11008      // 256 : W_op[:, :256] @ q
#define WS_PCOL  11264      // 256
#define WS_UOP   11520      // 256
#define WS_UCOL  11776      // 256
#define WS_AOP   12032      // 4*16 (9 used per t)
#define WS_ACOL  12096      // 4*64
#define WS_PIV   12864      // [0]=g_pivot [1]=l_pivot
#define WS_ACC   12872      // dot[4], cnt[4]
#define WS_TICKET 12880     // block completion ticket (float count)
#define WS_VHH   12896      // 256 : W_hh @ h_hist

#define NSEL_BLOCKS 64
#define NTBL_BLOCKS 782     // 782*256 = 200192 >= 200000; 200000 = 64*3125 exactly

// DPP-based partial-sum add (VALU pipe)
template<int CTRL>
__device__ __forceinline__ float dpp_add(float x) {
    int xi = __float_as_int(x);
    int yi = __builtin_amdgcn_update_dpp(0, xi, CTRL, 0xF, 0xF, true);
    return x + __int_as_float(yi);
}
#define DPP_XOR1 0xB1   // quad_perm [1,0,3,2]  (lane^1)
#define DPP_XOR2 0x4E   // quad_perm [2,3,0,1]  (lane^2)
#define DPP_HMIR 0x141  // row_half_mirror      (lane^7)
#define DPP_MIR  0x140  // row_mirror           (lane^15)

// full 64-lane sum, result in all lanes
__device__ __forceinline__ float reduce64(float v) {
    v = dpp_add<DPP_XOR1>(v);
    v = dpp_add<DPP_XOR2>(v);
    v = dpp_add<DPP_HMIR>(v);
    v = dpp_add<DPP_MIR>(v);
    v += __shfl_xor(v, 16);
    v += __shfl_xor(v, 32);
    return v;
}
// 16-lane-group sum, result in all lanes of the group
__device__ __forceinline__ float reduce16(float v) {
    v = dpp_add<DPP_XOR1>(v);
    v = dpp_add<DPP_XOR2>(v);
    v = dpp_add<DPP_HMIR>(v);
    v = dpp_add<DPP_MIR>(v);
    return v;
}

__device__ __forceinline__ float fast_tanh(float x) {
    float cx = fminf(15.f, fmaxf(-15.f, x));
    float e = __expf(2.f * cx);
    return __fdividef(e - 1.f, e + 1.f);
}

// h swizzle: pad 4 floats per 32 -> p-slices start on disjoint bank quads
__device__ __forceinline__ int swz(int i) { return i + ((i >> 5) << 2); }

// ---- X@Wx + b, and zero the accumulators/ticket ----
__global__ void k_xw(const int* __restrict__ iq, const float* __restrict__ E,
                     const float* __restrict__ Wx, const float* __restrict__ b,
                     float* __restrict__ ws) {
    int t = blockIdx.x;
    int i = threadIdx.x;
    if (t == 0 && i < 32) ws[WS_ACC + i] = 0.f;   // ACC[8] + TICKET + slack
    int word = iq[t];
    const float* erow = E + (long)word * H;
    float acc = b[i];
    #pragma unroll 8
    for (int j = 0; j < H; ++j) acc += erow[j] * Wx[j * H + i];
    ws[WS_XWB + t * H + i] = acc;
}

// ---- question RNN: 1024 threads, R=2 outputs x P=8 j-slices per thread ----
// swizzled h (conflict-free), Wh register-resident, DPP reduce, dbuf h.
__global__ __launch_bounds__(1024) void k_rnn(const float* __restrict__ Wh,
                      const int* __restrict__ lwi,
                      const float* __restrict__ U, const float* __restrict__ qn,
                      float* __restrict__ ws) {
    __shared__ __attribute__((aligned(16))) float hbuf[2][288];
    __shared__ __attribute__((aligned(16))) float xwb[QLEN][H];
    __shared__ float Z[NNUM][H];
    __shared__ float lg[10];
    int tid = threadIdx.x;       // 1024
    int g = tid >> 3;            // output pair 0..127 (outputs i = g*2+r)
    int p = tid & 7;             // j-slice 0..7      (j = p*32 .. p*32+31)

    // Wh fragment: w2[jj] = Wh[(p*32+jj)][g*2 .. g*2+1]
    float2 w2[32];
    #pragma unroll
    for (int jj = 0; jj < 32; ++jj)
        w2[jj] = *(const float2*)&Wh[(p * 32 + jj) * H + g * 2];

    // preload X@Wx+b into LDS (40 KB)
    {
        const float4* src = (const float4*)&ws[WS_XWB];
        float4* dst = (float4*)&xwb[0][0];
        for (int idx = tid; idx < QLEN * H / 4; idx += 1024) dst[idx] = src[idx];
    }
    if (tid < H) hbuf[0][swz(tid)] = 0.f;
    __syncthreads();

    int lw0 = lwi[0], lw1 = lwi[1], lw2 = lwi[2], lw3 = lwi[3], lw4 = lwi[4];
    int cur = 0;
    for (int t = 0; t < QLEN; ++t) {
        const float4* hv = (const float4*)&hbuf[cur][p * 36];  // swz(p*32) = p*36
        float a0 = 0.f, a1 = 0.f;
        #pragma unroll
        for (int q4 = 0; q4 < 8; ++q4) {
            float4 h4 = hv[q4];
            float2 wa = w2[q4 * 4 + 0];
            float2 wb = w2[q4 * 4 + 1];
            float2 wc = w2[q4 * 4 + 2];
            float2 wd = w2[q4 * 4 + 3];
            a0 += h4.x * wa.x; a1 += h4.x * wa.y;
            a0 += h4.y * wb.x; a1 += h4.y * wb.y;
            a0 += h4.z * wc.x; a1 += h4.z * wc.y;
            a0 += h4.w * wd.x; a1 += h4.w * wd.y;
        }
        // reduce over the 8 p-lanes
        a0 = dpp_add<DPP_XOR1>(a0); a0 = dpp_add<DPP_XOR2>(a0); a0 = dpp_add<DPP_HMIR>(a0);
        a1 = dpp_add<DPP_XOR1>(a1); a1 = dpp_add<DPP_XOR2>(a1); a1 = dpp_add<DPP_HMIR>(a1);
        if (p < 2) {
            float s = (p == 0) ? a0 : a1;
            int i = g * 2 + p;
            float hn = fast_tanh(xwb[t][i] + s);
            hbuf[cur ^ 1][swz(i)] = hn;
            if (t == lw0) Z[0][i] = hn;
            if (t == lw1) Z[1][i] = hn;
            if (t == lw2) Z[2][i] = hn;
            if (t == lw3) Z[3][i] = hn;
            if (t == lw4) Z[4][i] = hn;
        }
        __syncthreads();
        cur ^= 1;
    }
    if (tid < H) { ws[WS_Q + tid] = hbuf[cur][swz(tid)]; ws[WS_HHA + tid] = 0.f; }

    // pivot logits: 10 dots of 256, one 32-lane group each
    int grp = tid >> 5;
    int lane = tid & 31;
    if (grp < 10) {
        int u = grp / 5, n = grp % 5;
        float s = 0.f;
        #pragma unroll
        for (int k = 0; k < 8; ++k) {
            int j = lane + k * 32;
            s += Z[n][j] * U[u * H + j];
        }
        s += __shfl_xor(s, 1);
        s += __shfl_xor(s, 2);
        s += __shfl_xor(s, 4);
        s += __shfl_xor(s, 8);
        s += __shfl_xor(s, 16);
        if (lane == 0) lg[grp] = s;
    }
    __syncthreads();
    if (tid < 2) {
        float m = -1e30f;
        for (int n = 0; n < 5; ++n) m = fmaxf(m, lg[tid * 5 + n]);
        float e[5], s = 0.f;
        for (int n = 0; n < 5; ++n) { e[n] = expf(lg[tid * 5 + n] - m); s += e[n]; }
        float piv = 0.f;
        for (int n = 0; n < 5; ++n) piv += (e[n] / s) * qn[n];
        ws[WS_PIV + (tid == 0 ? 1 : 0)] = piv;   // PIV[0]=g, PIV[1]=l
    }
}

// ---- cooperative selector: P prologue + 4 timesteps (2 grid syncs each) ----
__global__ __launch_bounds__(256) void k_sel(const float* __restrict__ W_op,
                    const float* __restrict__ W_col, const float* __restrict__ W_hh,
                    const float* __restrict__ op_emb, const float* __restrict__ col_emb,
                    const float* __restrict__ W_hc, float* __restrict__ ws) {
    cg::grid_group grid = cg::this_grid();
    __shared__ float lgs[80];      // 73 logits
    __shared__ float aop_s[16];
    __shared__ float acol_s[64];
    __shared__ float c_s[2 * H];
    int tid = threadIdx.x;
    int b = blockIdx.x;
    int w = tid >> 6;
    int lane = tid & 63;

    // ---- prologue: P_op / P_col = W[:, :256] @ q ----
    {
        float4 qv = *(const float4*)&ws[WS_Q + lane * 4];
        #pragma unroll
        for (int k = 0; k < 2; ++k) {
            int o = b * 8 + w * 2 + k;   // 0..511
            const float* row = (o < H) ? (W_op + o * (2 * H) + lane * 4)
                                       : (W_col + (o - H) * (2 * H) + lane * 4);
            float4 wv = *(const float4*)row;
            float s = wv.x * qv.x + wv.y * qv.y + wv.z * qv.z + wv.w * qv.w;
            s = reduce64(s);
            if (lane == 0) {
                if (o < H) ws[WS_POP + o] = s; else ws[WS_PCOL + (o - H)] = s;
            }
        }
    }
    grid.sync();

    for (int t = 0; t < T_STEPS; ++t) {
        const float* hsrc = ws + ((t & 1) ? WS_HHB : WS_HHA);
        float* hdst = ws + ((t & 1) ? WS_HHA : WS_HHB);

        // ---- stage A: u_op, u_col, v_hh (768 dot-256, distributed) ----
        {
            float4 hv = *(const float4*)&hsrc[lane * 4];
            #pragma unroll
            for (int k = 0; k < 3; ++k) {
                int o = b * 12 + w * 3 + k;   // 0..767
                const float* row;
                if (o < H)            row = W_op + o * (2 * H) + H + lane * 4;
                else if (o < 2 * H)   row = W_col + (o - H) * (2 * H) + H + lane * 4;
                else                  row = W_hh + (o - 2 * H) * H + lane * 4;
                float4 wv = *(const float4*)row;
                float s = wv.x * hv.x + wv.y * hv.y + wv.z * hv.z + wv.w * hv.w;
                s = reduce64(s);
                if (lane == 0) {
                    if (o < H)          ws[WS_UOP + o] = fast_tanh(ws[WS_POP + o] + s);
                    else if (o < 2 * H) ws[WS_UCOL + (o - H)] = fast_tanh(ws[WS_PCOL + (o - 2 * H) + H] + s);
                    else                ws[WS_VHH + (o - 2 * H)] = s;
                }
            }
        }
        grid.sync();

        // ---- stage BC (every block, redundant): logits -> softmax -> c -> h slice ----
        // 1) logits: 73 dots of 256; 16-lane group per output
        {
            int g16 = tid >> 4, l16 = tid & 15;
            // hoist this lane's u slices (16 floats each)
            float4 uo0 = *(const float4*)&ws[WS_UOP + l16 * 16 + 0];
            float4 uo1 = *(const float4*)&ws[WS_UOP + l16 * 16 + 4];
            float4 uo2 = *(const float4*)&ws[WS_UOP + l16 * 16 + 8];
            float4 uo3 = *(const float4*)&ws[WS_UOP + l16 * 16 + 12];
            float4 uc0 = *(const float4*)&ws[WS_UCOL + l16 * 16 + 0];
            float4 uc1 = *(const float4*)&ws[WS_UCOL + l16 * 16 + 4];
            float4 uc2 = *(const float4*)&ws[WS_UCOL + l16 * 16 + 8];
            float4 uc3 = *(const float4*)&ws[WS_UCOL + l16 * 16 + 12];
            for (int o = g16; o < NOPS + COLSN; o += 16) {
                const float* row = (o < NOPS) ? (op_emb + o * H + l16 * 16)
                                              : (col_emb + (o - NOPS) * H + l16 * 16);
                float4 e0 = *(const float4*)&row[0];
                float4 e1 = *(const float4*)&row[4];
                float4 e2 = *(const float4*)&row[8];
                float4 e3 = *(const float4*)&row[12];
                float s;
                if (o < NOPS)
                    s = e0.x*uo0.x + e0.y*uo0.y + e0.z*uo0.z + e0.w*uo0.w
                      + e1.x*uo1.x + e1.y*uo1.y + e1.z*uo1.z + e1.w*uo1.w
                      + e2.x*uo2.x + e2.y*uo2.y + e2.z*uo2.z + e2.w*uo2.w
                      + e3.x*uo3.x + e3.y*uo3.y + e3.z*uo3.z + e3.w*uo3.w;
                else
                    s = e0.x*uc0.x + e0.y*uc0.y + e0.z*uc0.z + e0.w*uc0.w
                      + e1.x*uc1.x + e1.y*uc1.y + e1.z*uc1.z + e1.w*uc1.w
                      + e2.x*uc2.x + e2.y*uc2.y + e2.z*uc2.z + e2.w*uc2.w
                      + e3.x*uc3.x + e3.y*uc3.y + e3.z*uc3.z + e3.w*uc3.w;
                s = reduce16(s);
                if (l16 == 0) lgs[o] = s;
            }
        }
        __syncthreads();
        // 2) softmaxes
        if (tid == 0) {
            float m = -1e30f;
            for (int k = 0; k < NOPS; ++k) m = fmaxf(m, lgs[k]);
            float e[NOPS], s = 0.f;
            for (int k = 0; k < NOPS; ++k) { e[k] = expf(lgs[k] - m); s += e[k]; }
            float inv = 1.f / s;
            for (int k = 0; k < NOPS; ++k) {
                float a = e[k] * inv;
                aop_s[k] = a;
                if (b == 0) ws[WS_AOP + t * 16 + k] = a;
            }
        }
        if (w == 1) {  // wave 1: 64-wide col softmax
            float v = lgs[NOPS + lane];
            float m = v;
            for (int off = 1; off < 64; off <<= 1) m = fmaxf(m, __shfl_xor(m, off));
            float e = expf(v - m);
            float s = e;
            for (int off = 1; off < 64; off <<= 1) s += __shfl_xor(s, off);
            float a = __fdividef(e, s);
            acol_s[lane] = a;
            if (b == 0) ws[WS_ACOL + t * COLSN + lane] = a;
        }
        __syncthreads();
        // 3) c = [a_op@op_emb, a_col@col_emb]
        {
            float cop = 0.f;
            #pragma unroll
            for (int k = 0; k < NOPS; ++k) cop += aop_s[k] * op_emb[k * H + tid];
            c_s[tid] = cop;
            float ccol = 0.f;
            #pragma unroll
            for (int k = 0; k < COLSN; ++k) ccol += acol_s[k] * col_emb[k * H + tid];
            c_s[H + tid] = ccol;
        }
        __syncthreads();
        // 4) h slice: this block's 4 outputs (one per wave)
        {
            int o = b * 4 + w;   // 0..255
            const float* row = W_hc + o * (2 * H) + lane * 8;
            float4 w0 = *(const float4*)&row[0];
            float4 w1 = *(const float4*)&row[4];
            float4 c0 = *(const float4*)&c_s[lane * 8];
            float4 c1 = *(const float4*)&c_s[lane * 8 + 4];
            float s = w0.x*c0.x + w0.y*c0.y + w0.z*c0.z + w0.w*c0.w
                    + w1.x*c1.x + w1.y*c1.y + w1.z*c1.z + w1.w*c1.w;
            s = reduce64(s);
            if (lane == 0) hdst[o] = fast_tanh(s + ws[WS_VHH + o]);
        }
        grid.sync();
    }
}

// ---- table pass: coalesced LDS-staged loads, rs chain, lookup, reductions,
// ---- last block (atomic ticket) computes the scalar chain.
__global__ __launch_bounds__(256) void k_table(const float* __restrict__ table,
                                               float* __restrict__ ws,
                                               float* __restrict__ out) {
    __shared__ __attribute__((aligned(16))) float tile[4][64 * 68];  // 69.6 KB
    __shared__ float acol_l[4 * COLSN];
    __shared__ float aop_l[4 * 16];
    __shared__ float rs3[4][64];
    __shared__ float wred[4][8];
    int tid = threadIdx.x;
    int wid = tid >> 6;
    int lane = tid & 63;
    acol_l[tid] = ws[WS_ACOL + tid];
    if (tid < 64) aop_l[tid] = ws[WS_AOP + tid];
    float gp = ws[WS_PIV + 0];
    float lp = ws[WS_PIV + 1];

    long wv = (long)blockIdx.x * 4 + wid;
    long base = wv * 64;                    // first row of this wave's tile
    bool active = (base < ROWSN);           // ROWSN % 64 == 0: whole tile valid or not

    if (active) {
        const float* src = table + base * COLSN;
        #pragma unroll
        for (int s = 0; s < 16; ++s) {
            float4 v = *(const float4*)(src + s * 256 + lane * 4);
            int row = s * 4 + (lane >> 4);
            int col = (lane & 15) * 4;
            *(float4*)&tile[wid][row * 68 + col] = v;
        }
    }
    __syncthreads();

    float cv[4] = {0,0,0,0}, gs[4] = {0,0,0,0}, ls[4] = {0,0,0,0};
    if (active) {
        const float* tr = &tile[wid][lane * 68];
        #pragma unroll
        for (int c4 = 0; c4 < 16; ++c4) {
            float4 v = *(const float4*)&tr[c4 * 4];
            float xs[4] = {v.x, v.y, v.z, v.w};
            #pragma unroll
            for (int e = 0; e < 4; ++e) {
                int c = c4 * 4 + e;
                float x = xs[e];
                float gt = (x > gp) ? 1.f : 0.f;
                float lt = (x < lp) ? 1.f : 0.f;
                #pragma unroll
                for (int t = 0; t < 4; ++t) {
                    float a = acol_l[t * COLSN + c];
                    cv[t] += x * a;
                    gs[t] += gt * a;
                    ls[t] += lt * a;
                }
            }
        }
    }
    float prev1 = 1.f, prev2 = 1.f;
    float dotp[4], cntp[4];
    #pragma unroll
    for (int t = 0; t < 4; ++t) {
        dotp[t] = active ? prev1 * cv[t] : 0.f;
        cntp[t] = active ? prev1 : 0.f;
        float cg = aop_l[t*16+3], cl = aop_l[t*16+4], cmn = aop_l[t*16+5];
        float cmx = aop_l[t*16+6], co = aop_l[t*16+8];
        float cid = aop_l[t*16+0] + aop_l[t*16+1] + aop_l[t*16+2] + aop_l[t*16+7];
        float rsn = cg * gs[t] + cl * ls[t] + cmn * fminf(prev1, prev2)
                  + cmx * fmaxf(prev1, prev2) + co + cid * prev1;
        prev2 = prev1; prev1 = rsn;
    }
    rs3[wid][lane] = prev1 * aop_l[3*16+7];
    __syncthreads();

    // lookup write: coalesced 256B-per-instr scalar stores (out+1 is 4B-aligned only)
    if (active) {
        float* dst = out + 1 + base * COLSN;
        #pragma unroll
        for (int s = 0; s < 16; ++s) {
            int row = s * 4 + (lane >> 4);
            int col = (lane & 15) * 4;
            float r3 = rs3[wid][row];
            float* o4 = dst + s * 256 + lane * 4;
            o4[0] = r3 * acol_l[3 * COLSN + col + 0];
            o4[1] = r3 * acol_l[3 * COLSN + col + 1];
            o4[2] = r3 * acol_l[3 * COLSN + col + 2];
            o4[3] = r3 * acol_l[3 * COLSN + col + 3];
        }
    }

    // block-reduce dot[t], cnt[t] then one atomicAdd set per block
    #pragma unroll
    for (int t = 0; t < 4; ++t) {
        float d = dotp[t], cn = cntp[t];
        for (int off = 1; off < 64; off <<= 1) { d += __shfl_xor(d, off); cn += __shfl_xor(cn, off); }
        if (lane == 0) { wred[wid][t] = d; wred[wid][4 + t] = cn; }
    }
    __syncthreads();
    if (tid < 8) {
        float s = wred[0][tid] + wred[1][tid] + wred[2][tid] + wred[3][tid];
        atomicAdd(&ws[WS_ACC + tid], s);
    }
    __syncthreads();   // drains the ACC atomics (vmcnt) for all waves before ticket

    if (tid == 0) {
        float old = atomicAdd(&ws[WS_TICKET], 1.0f);
        if ((int)(old + 0.5f) == NTBL_BLOCKS - 1) {
            // last block: ACC is complete; read device-coherently via atomic RMW
            float d0 = atomicAdd(&ws[WS_ACC+0], 0.f), d1 = atomicAdd(&ws[WS_ACC+1], 0.f);
            float d2 = atomicAdd(&ws[WS_ACC+2], 0.f), d3 = atomicAdd(&ws[WS_ACC+3], 0.f);
            float c0 = atomicAdd(&ws[WS_ACC+4], 0.f), c1 = atomicAdd(&ws[WS_ACC+5], 0.f);
            float c2 = atomicAdd(&ws[WS_ACC+6], 0.f), c3 = atomicAdd(&ws[WS_ACC+7], 0.f);
            const float* a0 = &aop_l[0];
            const float* a1 = &aop_l[16];
            const float* a2 = &aop_l[32];
            const float* a3 = &aop_l[48];
            float s0 = a0[0]*d0 + a0[1]*c0;
            float s1 = a1[0]*d1 + a1[1]*c1 + a1[2]*(0.f - s0);
            float s2 = a2[0]*d2 + a2[1]*c2 + a2[2]*(0.f - s1);
            float s3 = a3[0]*d3 + a3[1]*c3 + a3[2]*(s0 - s2);
            out[0] = s3;
        }
    }
}

extern "C" void kernel_launch(void* const* d_in, const int* in_sizes, int n_in,
                              void* d_out, int out_size, void* d_ws, size_t ws_size,
                              hipStream_t stream) {
    const int*   iq      = (const int*)  d_in[0];
    const float* qn      = (const float*)d_in[1];
    const int*   lwi     = (const int*)  d_in[2];
    const float* table   = (const float*)d_in[3];
    const float* E       = (const float*)d_in[4];
    const float* Wx      = (const float*)d_in[5];
    const float* Wh      = (const float*)d_in[6];
    const float* b       = (const float*)d_in[7];
    const float* W_op    = (const float*)d_in[8];
    const float* op_emb  = (const float*)d_in[9];
    const float* W_col   = (const float*)d_in[10];
    const float* col_emb = (const float*)d_in[11];
    const float* U       = (const float*)d_in[12];
    const float* W_hc    = (const float*)d_in[13];
    const float* W_hh    = (const float*)d_in[14];
    float* out = (float*)d_out;
    float* ws  = (float*)d_ws;

    hipLaunchKernelGGL(k_xw,  dim3(QLEN), dim3(H),    0, stream, iq, E, Wx, b, ws);
    hipLaunchKernelGGL(k_rnn, dim3(1),    dim3(1024), 0, stream, Wh, lwi, U, qn, ws);

    {
        void* args[] = {(void*)&W_op, (void*)&W_col, (void*)&W_hh,
                        (void*)&op_emb, (void*)&col_emb, (void*)&W_hc, (void*)&ws};
        hipLaunchCooperativeKernel((void*)k_sel, dim3(NSEL_BLOCKS), dim3(256),
                                   args, 0, stream);
    }

    hipLaunchKernelGGL(k_table, dim3(NTBL_BLOCKS), dim3(256), 0, stream, table, ws, out);
}